// Round 3
// baseline (344.072 us; speedup 1.0000x reference)
//
#include <hip/hip_runtime.h>

// PINNLayer — NN=100000, NE=3200000. fp32 in, fp32 out.
// d_out fp32: [ result (NN) | out2 (NE,3) rows = [src,dst,val] ].
//
// Round-8: round-7's edge_scatter was transaction-bound (106us, 1.75TB/s,
// VALU 6.5%): per-record random 8B stores -> ~64 lines touched per wave store.
// Fix: LDS-staged multi-split. Records are histogrammed, bucket-sorted into a
// 16KB LDS staging buffer, then flushed with coalesced writes (~1.2KB
// contiguous per bucket per block). Windows widened to 16384 nodes (128KB LDS,
// proven in round-6) -> 7 windows, 14 combined buckets.
//   P1 edge_scatter: conv + out2 + LDS-sorted bucket scatter (1 tail atomic
//      per bucket per block). Overflow arena => correct under any skew.
//   P2 accum_b: grid = 7 windows x 32 slices; every record read exactly once;
//      flush = plain coalesced float4 partial stores. Zero global atomics.
//   P3 node_final_b: reduce 32 partials + compose.
// Fallback to the proven round-5 pipeline if ws_size too small.

#define WSH    14
#define WSZ    16384    // nodes per window (128KB LDS for two fp32 tables)
#define SLC    32       // slices per window -> grid 7*32 = 224 blocks
#define EPT    4        // edges per thread in edge_scatter
#define MAXWIN 16       // max windows supported
#define OVSLOT 32       // tail slot index for the overflow arena

// old-path constants (fallback)
#define OWSH 13
#define OWSZ 8192
#define OPB  16
#define OFPS 8192.0f
#define OQBIAS (1 << 20)
#define OQCLMP ((1 << 19) - 1)

// ---------------------------------------------------------------------------
// prep: conc gather; zero bucket tails (full path) or acc (fallback path).
__global__ __launch_bounds__(256) void prep(
    const float* __restrict__ od,
    float* __restrict__ conc,
    unsigned long long* __restrict__ acc,
    unsigned* __restrict__ tails,      // padded: tail[i] at tails[i<<4]
    int n_nodes)
{
    if (blockIdx.x == 0 && tails && threadIdx.x <= OVSLOT)
        tails[(size_t)threadIdx.x << 4] = 0u;
    int n = blockIdx.x * blockDim.x + threadIdx.x;
    if (n >= n_nodes) return;
    conc[n] = od[(long long)n * 48 + 45];   // origin_data[n,15,0]
    if (acc) acc[n] = 0ULL;
}

// ---------------------------------------------------------------------------
// P1 (full): conv + out2 + LDS-staged bucket scatter.
// val[e] = b + sum_{j<36} flow[e*12+j] * w_re[j],
//   w_re[kh*12+kw*4+i] = conv_w[i*9+kh*3+kw]
// A-record {s, val} -> bucket s>>WSH;  B-record {d, val*conc[s]} -> bucket n_win+(d>>WSH)
__global__ __launch_bounds__(256) void edge_scatter(
    const float* __restrict__ flow, const int* __restrict__ ei,
    const float* __restrict__ conv_w, const float* __restrict__ conv_b,
    const float* __restrict__ conc,
    float* __restrict__ out2,
    uint2* __restrict__ rec,           // NB buckets x cap records
    uint2* __restrict__ ovf,
    unsigned* __restrict__ tails,
    int n_edges, int n_win, unsigned cap, unsigned ocap)
{
    __shared__ float    w[40];
    __shared__ unsigned cnt[2 * MAXWIN];
    __shared__ unsigned sst[2 * MAXWIN];   // exclusive scan of cnt
    __shared__ unsigned bas[2 * MAXWIN];   // global reservation base
    __shared__ unsigned stot;
    __shared__ uint2    stg[512 * EPT];    // 2048 recs * 8B = 16KB
    __shared__ unsigned dsti[512 * EPT];   // 8KB

    const int t  = threadIdx.x;
    const int NB = 2 * n_win;
    if (t < 36) {
        int i  = t & 3;
        int kw = (t >> 2) % 3;
        int kh = t / 12;
        w[t] = conv_w[i * 9 + kh * 3 + kw];
    }
    if (t == 36) w[36] = conv_b[0];
    if (t < 2 * MAXWIN) cnt[t] = 0u;
    __syncthreads();

    const long long eb = (long long)blockIdx.x * (256 * EPT) + t;
    uint2    payA[EPT], payB[EPT];
    unsigned posA[EPT], posB[EPT];

    // ---- pass 1: conv + out2 + histogram ----
#pragma unroll
    for (int k = 0; k < EPT; ++k) {
        posA[k] = 0xffffffffu; posB[k] = 0xffffffffu;
        long long e = eb + (long long)k * 256;
        if (e < n_edges) {
            int s = ei[e];
            int d = ei[n_edges + e];
            const float4* fp = (const float4*)(flow + e * 12);
            float acc = w[36];
#pragma unroll
            for (int q = 0; q < 9; ++q) {
                float4 v = fp[q];
                acc = fmaf(v.x, w[q * 4 + 0], acc);
                acc = fmaf(v.y, w[q * 4 + 1], acc);
                acc = fmaf(v.z, w[q * 4 + 2], acc);
                acc = fmaf(v.w, w[q * 4 + 3], acc);
            }
            float cs = conc[s];                 // L2-resident gather (400KB)
            float* o = out2 + e * 3;
            o[0] = (float)s;
            o[1] = (float)d;
            o[2] = acc;
            if (s != d) {
                payA[k].x = (unsigned)s; payA[k].y = __float_as_uint(acc);
                payB[k].x = (unsigned)d; payB[k].y = __float_as_uint(acc * cs);
                posA[k] = atomicAdd(&cnt[(unsigned)s >> WSH], 1u);
                posB[k] = atomicAdd(&cnt[n_win + ((unsigned)d >> WSH)], 1u);
            }
        }
    }
    __syncthreads();

    // ---- pass 2: scan + global reservation ----
    if (t == 0) {
        unsigned a = 0;
        for (int b = 0; b < NB; ++b) { sst[b] = a; a += cnt[b]; }
        stot = a;
    }
    if (t < NB && cnt[t]) bas[t] = atomicAdd(&tails[(size_t)t << 4], cnt[t]);
    __syncthreads();

    // ---- pass 3: bucket-sorted staging ----
#pragma unroll
    for (int k = 0; k < EPT; ++k) {
        if (posA[k] != 0xffffffffu) {
            unsigned b = payA[k].x >> WSH;
            unsigned i = sst[b] + posA[k];
            unsigned g = bas[b] + posA[k];
            stg[i] = payA[k];
            if (g < cap) {
                dsti[i] = b * cap + g;
            } else {
                dsti[i] = 0xffffffffu;
                unsigned os = atomicAdd(&tails[(size_t)OVSLOT << 4], 1u);
                if (os < ocap) ovf[os] = payA[k];          // bit31=0 -> A
            }
        }
        if (posB[k] != 0xffffffffu) {
            unsigned b = n_win + (payB[k].x >> WSH);
            unsigned i = sst[b] + posB[k];
            unsigned g = bas[b] + posB[k];
            stg[i] = payB[k];
            if (g < cap) {
                dsti[i] = b * cap + g;
            } else {
                dsti[i] = 0xffffffffu;
                unsigned os = atomicAdd(&tails[(size_t)OVSLOT << 4], 1u);
                if (os < ocap) { uint2 r = payB[k]; r.x |= 0x80000000u; ovf[os] = r; }
            }
        }
    }
    __syncthreads();

    // ---- pass 4: coalesced flush (consecutive slots -> consecutive dst) ----
    unsigned tot = stot;
    for (unsigned i = t; i < tot; i += 256) {
        unsigned u = dsti[i];
        if (u != 0xffffffffu) rec[u] = stg[i];
    }
}

// ---------------------------------------------------------------------------
// P2 (full): each (window, slice) block reads its bucket slices exactly once.
__global__ __launch_bounds__(1024) void accum_b(
    const uint2* __restrict__ rec, const uint2* __restrict__ ovf,
    const unsigned* __restrict__ tails,
    float* __restrict__ pA, float* __restrict__ pB,
    int n_win, unsigned cap, unsigned ocap)
{
    __shared__ float tA[WSZ];
    __shared__ float tB[WSZ];

    const int w  = blockIdx.x / SLC;
    const int sl = blockIdx.x % SLC;
    const int t  = threadIdx.x;

    float4 z = make_float4(0.f, 0.f, 0.f, 0.f);
    for (int i = t; i < (WSZ >> 2); i += 1024) {
        ((float4*)tA)[i] = z; ((float4*)tB)[i] = z;
    }
    __syncthreads();

    {   // A bucket slice
        unsigned nA = min(tails[(size_t)w << 4], cap);
        const uint2* r = rec + (size_t)w * cap;
        unsigned i0 = (unsigned)((unsigned long long)nA * sl / SLC);
        unsigned i1 = (unsigned)((unsigned long long)nA * (sl + 1) / SLC);
        for (unsigned i = i0 + t; i < i1; i += 1024) {
            uint2 q = r[i];
            atomicAdd(&tA[q.x & (WSZ - 1)], __uint_as_float(q.y));
        }
    }
    {   // B bucket slice
        unsigned nB = min(tails[(size_t)(n_win + w) << 4], cap);
        const uint2* r = rec + (size_t)(n_win + w) * cap;
        unsigned i0 = (unsigned)((unsigned long long)nB * sl / SLC);
        unsigned i1 = (unsigned)((unsigned long long)nB * (sl + 1) / SLC);
        for (unsigned i = i0 + t; i < i1; i += 1024) {
            uint2 q = r[i];
            atomicAdd(&tB[q.x & (WSZ - 1)], __uint_as_float(q.y));
        }
    }
    {   // overflow arena (empty for non-adversarial inputs)
        unsigned no = min(tails[(size_t)OVSLOT << 4], ocap);
        if (no) {
            unsigned i0 = (unsigned)((unsigned long long)no * sl / SLC);
            unsigned i1 = (unsigned)((unsigned long long)no * (sl + 1) / SLC);
            for (unsigned i = i0 + t; i < i1; i += 1024) {
                uint2 q = ovf[i];
                unsigned node = q.x & 0x7fffffffu;
                if ((int)(node >> WSH) == w) {
                    if (q.x >> 31) atomicAdd(&tB[node & (WSZ - 1)], __uint_as_float(q.y));
                    else           atomicAdd(&tA[node & (WSZ - 1)], __uint_as_float(q.y));
                }
            }
        }
    }
    __syncthreads();

    // Flush: plain coalesced float4 stores — no atomics.
    float* dA = pA + ((size_t)blockIdx.x << WSH);
    float* dB = pB + ((size_t)blockIdx.x << WSH);
    for (int i = t; i < (WSZ >> 2); i += 1024) {
        ((float4*)dA)[i] = ((const float4*)tA)[i];
        ((float4*)dB)[i] = ((const float4*)tB)[i];
    }
}

// ---------------------------------------------------------------------------
// P3 (full): reduce SLC partials and compose result.
__global__ __launch_bounds__(256) void node_final_b(
    const float* __restrict__ od,
    const float* __restrict__ conc,
    const float* __restrict__ pA,
    const float* __restrict__ pB,
    float* __restrict__ out, int n_nodes)
{
    int n = blockIdx.x * blockDim.x + threadIdx.x;
    if (n >= n_nodes) return;

    const int w = n >> WSH, i = n & (WSZ - 1);
    size_t base = ((size_t)(w * SLC) << WSH) + i;
    float a0 = 0.f, a1 = 0.f, b0 = 0.f, b1 = 0.f;
#pragma unroll
    for (int sl = 0; sl < SLC; sl += 2) {
        a0 += pA[base + ((size_t)(sl + 0) << WSH)];
        a1 += pA[base + ((size_t)(sl + 1) << WSH)];
        b0 += pB[base + ((size_t)(sl + 0) << WSH)];
        b1 += pB[base + ((size_t)(sl + 1) << WSH)];
    }
    float a = a0 + a1, b = b0 + b1;

    long long bi = (long long)n * 48 + 45;
    float c  = conc[n];
    float p  = od[bi + 1];
    float is = 1.0f / od[bi + 2];

    float r = c;
    if (n != n_nodes - 1)
        r += (b - a * c) * is + 0.0052f * p * is;
    out[n] = r;
}

// ---------------------------------------------------------------------------
// Fallback path (round-5 proven): flat records + windowed scan + u64 atomics.
__global__ __launch_bounds__(256) void edge_conv_o(
    const float* __restrict__ flow, const int* __restrict__ ei,
    const float* __restrict__ conv_w, const float* __restrict__ conv_b,
    float* __restrict__ out2, int n_edges)
{
    __shared__ float w[40];
    int t = threadIdx.x;
    if (t < 36) {
        int i  = t & 3;
        int kw = (t >> 2) % 3;
        int kh = t / 12;
        w[t] = conv_w[i * 9 + kh * 3 + kw];
    }
    if (t == 36) w[36] = conv_b[0];
    __syncthreads();

    int e = blockIdx.x * blockDim.x + t;
    if (e >= n_edges) return;

    const float4* fp = (const float4*)(flow + (long long)e * 12);
    float acc = w[36];
#pragma unroll
    for (int q = 0; q < 9; ++q) {
        float4 v = fp[q];
        acc = fmaf(v.x, w[q * 4 + 0], acc);
        acc = fmaf(v.y, w[q * 4 + 1], acc);
        acc = fmaf(v.z, w[q * 4 + 2], acc);
        acc = fmaf(v.w, w[q * 4 + 3], acc);
    }

    float* o = out2 + (long long)e * 3;
    o[0] = (float)ei[e];
    o[1] = (float)ei[n_edges + e];
    o[2] = acc;
}

__global__ __launch_bounds__(1024) void accum_o(
    const float* __restrict__ out2,
    const float* __restrict__ conc,
    unsigned long long* __restrict__ acc,
    int n_edges, int n_nodes)
{
    __shared__ float tA[OWSZ];
    __shared__ float tB[OWSZ];

    const int w    = blockIdx.x / OPB;
    const int sl   = blockIdx.x % OPB;
    const int base = w << OWSH;

    for (int i = threadIdx.x; i < OWSZ; i += 1024) { tA[i] = 0.f; tB[i] = 0.f; }
    __syncthreads();

    const long long e0 = (long long)sl * n_edges / OPB;
    const long long e1 = (long long)(sl + 1) * n_edges / OPB;
    for (long long e = e0 + threadIdx.x; e < e1; e += 1024) {
        const float* r = out2 + e * 3;
        float fs = r[0], fd = r[1], v = r[2];
        int s = (int)fs, d = (int)fd;
        if (s == d) continue;
        if ((s >> OWSH) == w) atomicAdd(&tA[s - base], v);
        if ((d >> OWSH) == w) atomicAdd(&tB[d - base], v * conc[s]);
    }
    __syncthreads();

    for (int i = threadIdx.x; i < OWSZ; i += 1024) {
        int n = base + i;
        if (n >= n_nodes) continue;
        float a = tA[i], b = tB[i];
        if (a == 0.f && b == 0.f) continue;
        int qa = __float2int_rn(a * OFPS);
        int qb = __float2int_rn(b * OFPS);
        qa = min(max(qa, -OQCLMP), OQCLMP);
        qb = min(max(qb, -OQCLMP), OQCLMP);
        unsigned long long enc =
            ((unsigned long long)(unsigned)(qa + OQBIAS) << 37) +
            ((unsigned long long)(unsigned)(qb + OQBIAS) << 10) + 1ULL;
        atomicAdd(acc + n, enc);
    }
}

__global__ __launch_bounds__(256) void node_final_o(
    const float* __restrict__ od,
    const float* __restrict__ conc,
    const unsigned long long* __restrict__ acc,
    float* __restrict__ out, int n_nodes)
{
    int n = blockIdx.x * blockDim.x + threadIdx.x;
    if (n >= n_nodes) return;

    unsigned long long t = acc[n];
    long long cnt = (long long)(t & 1023ULL);
    unsigned long long t2 = t >> 10;
    long long sbr = (long long)(t2 & ((1ULL << 27) - 1));
    long long sar = (long long)(t2 >> 27);
    float a = (float)(sar - cnt * OQBIAS) * (1.0f / OFPS);
    float b = (float)(sbr - cnt * OQBIAS) * (1.0f / OFPS);

    long long bi = (long long)n * 48 + 45;
    float c  = conc[n];
    float p  = od[bi + 1];
    float is = 1.0f / od[bi + 2];

    float r = c;
    if (n != n_nodes - 1)
        r += (b - a * c) * is + 0.0052f * p * is;
    out[n] = r;
}

// ---------------------------------------------------------------------------
extern "C" void kernel_launch(void* const* d_in, const int* in_sizes, int n_in,
                              void* d_out, int out_size, void* d_ws, size_t ws_size,
                              hipStream_t stream) {
    const float* od   = (const float*)d_in[0];
    const float* flow = (const float*)d_in[1];
    const float* cw   = (const float*)d_in[2];
    const float* cb   = (const float*)d_in[3];
    const int*   ei   = (const int*)d_in[4];

    const int n_nodes = in_sizes[0] / 48;
    const int n_edges = in_sizes[4] / 2;

    float* out_res = (float*)d_out;        // (NN,)
    float* out2    = out_res + n_nodes;    // (NE,3)

    dim3 blk(256);
    dim3 grid_nodes((n_nodes + 255) / 256);

    // --- full-path workspace layout -------------------------------------
    const int n_win = (n_nodes + WSZ - 1) >> WSH;                 // 7
    const int NB    = 2 * n_win;                                  // 14
    const unsigned cap  = (unsigned)(n_edges / (n_win > 0 ? n_win : 1))
                        + (unsigned)(n_edges / 8) + 4096u;        // expected + slack
    const unsigned ocap = (unsigned)(2ULL * (unsigned long long)n_edges);

    size_t off = 0;
    size_t o_conc  = off; off += (((size_t)n_nodes * 4) + 255) & ~255ULL;
    size_t o_tails = off; off += ((OVSLOT + 1) * 16 * 4 + 255) & ~255ULL;
    size_t o_rec   = off; off += (((size_t)NB * cap * 8) + 255) & ~255ULL;
    size_t o_ovf   = off; off += (((size_t)ocap * 8) + 255) & ~255ULL;
    size_t o_pA    = off; off += (((size_t)n_win * SLC * WSZ * 4) + 255) & ~255ULL;
    size_t o_pB    = off; off += (((size_t)n_win * SLC * WSZ * 4) + 255) & ~255ULL;
    const bool full = (ws_size >= off) && (n_win <= MAXWIN);

    float* conc = (float*)((char*)d_ws + o_conc);

    if (full) {
        unsigned* tails = (unsigned*)((char*)d_ws + o_tails);
        uint2* rec = (uint2*)((char*)d_ws + o_rec);
        uint2* ovf = (uint2*)((char*)d_ws + o_ovf);
        float* pA  = (float*)((char*)d_ws + o_pA);
        float* pB  = (float*)((char*)d_ws + o_pB);

        dim3 grid_es((n_edges + 256 * EPT - 1) / (256 * EPT));    // 3125

        prep<<<grid_nodes, blk, 0, stream>>>(od, conc, nullptr, tails, n_nodes);
        edge_scatter<<<grid_es, blk, 0, stream>>>(flow, ei, cw, cb, conc,
                                                  out2, rec, ovf, tails,
                                                  n_edges, n_win, cap, ocap);
        accum_b<<<dim3(n_win * SLC), dim3(1024), 0, stream>>>(
            rec, ovf, tails, pA, pB, n_win, cap, ocap);
        node_final_b<<<grid_nodes, blk, 0, stream>>>(od, conc, pA, pB,
                                                     out_res, n_nodes);
    } else {
        // round-5 pipeline
        unsigned long long* acc =
            (unsigned long long*)((char*)d_ws + (((size_t)n_nodes * 4 + 7) / 8 * 8));
        const int n_win_o = (n_nodes + OWSZ - 1) >> OWSH;
        dim3 grid_edges((n_edges + 255) / 256);

        prep<<<grid_nodes, blk, 0, stream>>>(od, conc, acc, nullptr, n_nodes);
        edge_conv_o<<<grid_edges, blk, 0, stream>>>(flow, ei, cw, cb, out2, n_edges);
        accum_o<<<dim3(n_win_o * OPB), dim3(1024), 0, stream>>>(
            out2, conc, acc, n_edges, n_nodes);
        node_final_o<<<grid_nodes, blk, 0, stream>>>(od, conc, acc,
                                                     out_res, n_nodes);
    }
}